// Round 14
// baseline (785.018 us; speedup 1.0000x reference)
//
#include <hip/hip_runtime.h>
#include <hip/hip_cooperative_groups.h>

// Disable FMA contraction so float rounding matches the numpy reference
// op-for-op (threshold compares at 0.5 and argmax ties depend on it).
#pragma clang fp contract(off)

namespace cg = cooperative_groups;

#define BB 32     // batch
#define NN 100    // gt boxes per image
#define PP 8732   // priors
#define CH 16     // j-chunk for the transposed row-max reduce
#define LDW 257   // padded row stride (u32) -> 2-way banks only (free)
#define NBX 35    // blocks along the prior axis

// -------------------------------------------------------------------------
// FUSED cooperative kernel (r14): phase 1 = the verified r1 IoU/match pass
// (best-measured structure, ~37us); grid.sync(); phase 2 = encode.
//  - m8 is GONE: each block encodes the same 256 priors it matched, so
//    best_j / best_ov / pr survive in registers across the grid sync.
//  - Row-key partials cross blocks (and XCDs): stored with agent-scope
//    RELEASE atomics, merged with agent-scope ACQUIRE loads (G16: plain
//    stores may sit dirty in a producer XCD's non-coherent L2).
//  - Key (iou<<32)|~p, strict-> scans, phantom-lane handling, forced-match
//    scatter (atomicMax = last-write-wins on j), and all encode math are
//    bit-identical to the verified two-kernel scheme.
//  - Exact IEEE f32 division kept -> bit-identical decisions vs reference.
// Co-residency: LDS ~30.8 KB -> 5 blocks/CU x 256 CUs = 1280 >= 1120.
// -------------------------------------------------------------------------
__global__ __launch_bounds__(256) void k_fused(
    const float* __restrict__ gt,        // [B,N,4] xyxy
    const float* __restrict__ priors,    // [P,4] cxcywh
    const int*   __restrict__ labels,    // [B,N]
    unsigned long long* __restrict__ part,  // [B][NBX][NN] row-key partials
    float* __restrict__ loc_out,         // [B,P,4]
    float* __restrict__ conf_out)        // [B,P]
{
    __shared__ unsigned int s_iou[CH * LDW];          // 16.4 KB
    __shared__ unsigned long long s_part[NN][17];     // 13.6 KB
    __shared__ float s_area[NN];                      // 400 B
    __shared__ int s_forced[256];                     // 1 KB

    const int b = blockIdx.y;
    const int t = threadIdx.x;
    const int p = blockIdx.x * 256 + t;
    const bool valid = p < PP;
    const int pc = valid ? p : (PP - 1);

    // wave-uniform base: compiler scalarizes these loads (s_load_dwordx4)
    const float4* __restrict__ gtb =
        reinterpret_cast<const float4*>(gt) + b * NN;

    if (t < NN) {
        float4 g = gtb[t];                // per-thread gather here (vector)
        s_area[t] = (g.z - g.x) * (g.w - g.y);
    }

    const float4 pr = reinterpret_cast<const float4*>(priors)[pc];
    const float px1 = pr.x - pr.z * 0.5f;
    const float py1 = pr.y - pr.w * 0.5f;
    const float px2 = pr.x + pr.z * 0.5f;
    const float py2 = pr.y + pr.w * 0.5f;
    const float area_b = (px2 - px1) * (py2 - py1);

    float best_ov = -1.0f;
    int best_j = 0;

    __syncthreads();   // s_area ready

    for (int jc = 0; jc < NN; jc += CH) {
        const int nr = (NN - jc) < CH ? (NN - jc) : CH;

        #pragma unroll
        for (int jj = 0; jj < CH; ++jj) {
            if (jj >= nr) break;
            float4 g = gtb[jc + jj];                 // uniform -> SGPRs
            float area_a = s_area[jc + jj];          // broadcast ds_read
            float ltx = fmaxf(g.x, px1), lty = fmaxf(g.y, py1);
            float rbx = fminf(g.z, px2), rby = fminf(g.w, py2);
            float w = fmaxf(rbx - ltx, 0.0f), h = fmaxf(rby - lty, 0.0f);
            float inter = w * h;
            float iou = inter / (area_a + area_b - inter + 1e-6f);
            if (iou > best_ov) { best_ov = iou; best_j = jc + jj; }
            s_iou[jj * LDW + t] = __float_as_uint(iou);  // iou>=0: uint order
        }
        __syncthreads();

        // phase A: 16 threads per row, each scans 16 ascending-p columns
        {
            const int r = t & 15;
            const int s = t >> 4;
            if (r < nr) {
                const unsigned int* row = s_iou + r * LDW + s * 16;
                unsigned int bb = row[0];
                int bi = 0;
                #pragma unroll
                for (int i = 1; i < 16; ++i) {
                    unsigned int v = row[i];
                    if (v > bb) { bb = v; bi = i; }   // strict > = min p
                }
                int pw = blockIdx.x * 256 + s * 16 + bi;
                s_part[jc + r][s] = ((unsigned long long)bb << 32) |
                                    (unsigned int)(~pw);
            }
        }
        __syncthreads();   // s_iou reusable next chunk; s_part visible
    }

    // publish per-block row keys: agent-scope release (cross-XCD visible)
    if (t < NN) {
        unsigned long long best = s_part[t][0];
        #pragma unroll
        for (int s = 1; s < 16; ++s) {
            unsigned long long k = s_part[t][s];
            if (k > best) best = k;                   // ~p breaks iou ties
        }
        __hip_atomic_store(
            &part[((size_t)b * NBX + blockIdx.x) * NN + t], best,
            __ATOMIC_RELEASE, __HIP_MEMORY_SCOPE_AGENT);
    }

    // ---------------- grid-wide barrier ----------------
    cg::this_grid().sync();

    // ---------------- phase 2: encode (old k_encode, m8-free) -----------
    s_forced[t] = -1;
    __syncthreads();
    if (t < NN) {
        const unsigned long long* q = part + (size_t)b * NBX * NN + t;
        unsigned long long best = __hip_atomic_load(
            &q[0], __ATOMIC_ACQUIRE, __HIP_MEMORY_SCOPE_AGENT);
        #pragma unroll 5
        for (int bx = 1; bx < NBX; ++bx) {
            unsigned long long k = __hip_atomic_load(
                &q[(size_t)bx * NN], __ATOMIC_ACQUIRE,
                __HIP_MEMORY_SCOPE_AGENT);
            if (k > best) best = k;
        }
        int kp = (int)~(unsigned int)(best & 0xFFFFFFFFull);
        int lp = kp - blockIdx.x * 256;
        if ((unsigned)lp < 256u) atomicMax(&s_forced[lp], t);
    }
    __syncthreads();

    const int forced_j = s_forced[t];
    const int j    = (forced_j >= 0) ? forced_j : best_j;
    const int lab  = labels[b * NN + j];
    const int conf = (forced_j < 0 && (best_ov < 0.5f)) ? 0 : (lab + 1);

    const float4 g = gtb[j];            // divergent float4 gather (L2-hot)
    const float mcx = (g.x + g.z) * 0.5f;
    const float mcy = (g.y + g.w) * 0.5f;
    const float mw  = fmaxf(g.z - g.x, 1e-6f);
    const float mh  = fmaxf(g.w - g.y, 1e-6f);
    const float gcx = (mcx - pr.x) / (0.1f * pr.z);
    const float gcy = (mcy - pr.y) / (0.1f * pr.w);
    const float gw  = logf(mw / pr.z) / 0.2f;
    const float gh  = logf(mh / pr.w) / 0.2f;

    if (valid) {
        reinterpret_cast<float4*>(loc_out)[b * PP + p] =
            make_float4(gcx, gcy, gw, gh);
        conf_out[b * PP + p] = (float)conf;
    }
}

// -------------------------------------------------------------------------
// Fallback pair (the verified r1 two-kernel path) if cooperative launch is
// refused (capture or occupancy). Bit-identical results.
// -------------------------------------------------------------------------
__global__ __launch_bounds__(256) void k_iou_pass(
    const float* __restrict__ gt, const float* __restrict__ priors,
    unsigned long long* __restrict__ red, unsigned char* __restrict__ m8)
{
    __shared__ unsigned int s_iou[CH * LDW];
    __shared__ unsigned long long s_part[NN][17];
    __shared__ float s_area[NN];

    const int b = blockIdx.y;
    const int t = threadIdx.x;
    const int p = blockIdx.x * 256 + t;
    const bool valid = p < PP;
    const int pc = valid ? p : (PP - 1);

    const float4* __restrict__ gtb =
        reinterpret_cast<const float4*>(gt) + b * NN;

    if (t < NN) {
        float4 g = gtb[t];
        s_area[t] = (g.z - g.x) * (g.w - g.y);
    }

    const float4 pr = reinterpret_cast<const float4*>(priors)[pc];
    const float px1 = pr.x - pr.z * 0.5f;
    const float py1 = pr.y - pr.w * 0.5f;
    const float px2 = pr.x + pr.z * 0.5f;
    const float py2 = pr.y + pr.w * 0.5f;
    const float area_b = (px2 - px1) * (py2 - py1);

    float best_ov = -1.0f;
    int best_j = 0;

    __syncthreads();

    for (int jc = 0; jc < NN; jc += CH) {
        const int nr = (NN - jc) < CH ? (NN - jc) : CH;
        #pragma unroll
        for (int jj = 0; jj < CH; ++jj) {
            if (jj >= nr) break;
            float4 g = gtb[jc + jj];
            float area_a = s_area[jc + jj];
            float ltx = fmaxf(g.x, px1), lty = fmaxf(g.y, py1);
            float rbx = fminf(g.z, px2), rby = fminf(g.w, py2);
            float w = fmaxf(rbx - ltx, 0.0f), h = fmaxf(rby - lty, 0.0f);
            float inter = w * h;
            float iou = inter / (area_a + area_b - inter + 1e-6f);
            if (iou > best_ov) { best_ov = iou; best_j = jc + jj; }
            s_iou[jj * LDW + t] = __float_as_uint(iou);
        }
        __syncthreads();
        {
            const int r = t & 15;
            const int s = t >> 4;
            if (r < nr) {
                const unsigned int* row = s_iou + r * LDW + s * 16;
                unsigned int bb = row[0];
                int bi = 0;
                #pragma unroll
                for (int i = 1; i < 16; ++i) {
                    unsigned int v = row[i];
                    if (v > bb) { bb = v; bi = i; }
                }
                int pw = blockIdx.x * 256 + s * 16 + bi;
                s_part[jc + r][s] = ((unsigned long long)bb << 32) |
                                    (unsigned int)(~pw);
            }
        }
        __syncthreads();
    }

    if (t < NN) {
        unsigned long long best = s_part[t][0];
        #pragma unroll
        for (int s = 1; s < 16; ++s) {
            unsigned long long k = s_part[t][s];
            if (k > best) best = k;
        }
        red[((size_t)b * NBX + blockIdx.x) * NN + t] = best;
    }
    if (valid) {
        m8[b * PP + p] =
            (unsigned char)(best_j | ((best_ov < 0.5f) ? 0x80 : 0));
    }
}

__global__ __launch_bounds__(256) void k_encode(
    const float* __restrict__ gt, const int* __restrict__ labels,
    const float* __restrict__ priors,
    const unsigned long long* __restrict__ red,
    const unsigned char* __restrict__ m8,
    float* __restrict__ loc_out, float* __restrict__ conf_out)
{
    __shared__ int s_forced[256];

    const int b = blockIdx.y;
    const int t = threadIdx.x;
    const int p = blockIdx.x * 256 + t;

    s_forced[t] = -1;
    __syncthreads();
    if (t < NN) {
        const unsigned long long* q = red + (size_t)b * NBX * NN + t;
        unsigned long long best = q[0];
        #pragma unroll 5
        for (int bx = 1; bx < NBX; ++bx) {
            unsigned long long k = q[(size_t)bx * NN];
            if (k > best) best = k;
        }
        int kp = (int)~(unsigned int)(best & 0xFFFFFFFFull);
        int lp = kp - blockIdx.x * 256;
        if ((unsigned)lp < 256u) atomicMax(&s_forced[lp], t);
    }
    __syncthreads();

    if (p >= PP) return;
    const int forced_j = s_forced[t];

    const unsigned char m = m8[b * PP + p];
    const int j    = (forced_j >= 0) ? forced_j : (m & 0x7f);
    const int lab  = labels[b * NN + j];
    const int conf = (forced_j < 0 && (m & 0x80)) ? 0 : (lab + 1);

    const float4 pr = reinterpret_cast<const float4*>(priors)[p];
    const float4 g  = reinterpret_cast<const float4*>(gt)[b * NN + j];
    const float mcx = (g.x + g.z) * 0.5f;
    const float mcy = (g.y + g.w) * 0.5f;
    const float mw  = fmaxf(g.z - g.x, 1e-6f);
    const float mh  = fmaxf(g.w - g.y, 1e-6f);
    const float gcx = (mcx - pr.x) / (0.1f * pr.z);
    const float gcy = (mcy - pr.y) / (0.1f * pr.w);
    const float gw  = logf(mw / pr.z) / 0.2f;
    const float gh  = logf(mh / pr.w) / 0.2f;

    reinterpret_cast<float4*>(loc_out)[b * PP + p] =
        make_float4(gcx, gcy, gw, gh);
    conf_out[b * PP + p] = (float)conf;
}

extern "C" void kernel_launch(void* const* d_in, const int* in_sizes, int n_in,
                              void* d_out, int out_size, void* d_ws, size_t ws_size,
                              hipStream_t stream) {
    const float* gt     = (const float*)d_in[0];  // [32,100,4] f32
    const int*   labels = (const int*)  d_in[1];  // [32,100] i32
    const float* priors = (const float*)d_in[2];  // [8732,4] f32

    float* loc  = (float*)d_out;                         // [32,8732,4]
    float* conf = (float*)d_out + (size_t)BB * PP * 4;   // [32,8732]

    const size_t part_bytes = (size_t)BB * NBX * NN * 8;   // 896,000
    const size_t m8_bytes   = (size_t)BB * PP;             // 279,424
    dim3 grid(NBX, BB);

    unsigned long long* part = (unsigned long long*)d_ws;

    bool coop_ok = false;
    if (ws_size >= part_bytes) {
        void* args[] = {(void*)&gt, (void*)&priors, (void*)&labels,
                        (void*)&part, (void*)&loc, (void*)&conf};
        hipError_t e = hipLaunchCooperativeKernel(
            (const void*)k_fused, grid, dim3(256), args, 0, stream);
        if (e == hipSuccess) {
            coop_ok = true;
        } else {
            (void)hipGetLastError();   // clear the error, fall back
        }
    }

    if (!coop_ok && ws_size >= part_bytes + m8_bytes) {
        unsigned char* m8 = (unsigned char*)d_ws + part_bytes;
        k_iou_pass<<<grid, 256, 0, stream>>>(gt, priors, part, m8);
        k_encode<<<grid, 256, 0, stream>>>(gt, labels, priors, part,
                                           m8, loc, conf);
    }
}

// Round 15
// 103.007 us; speedup vs baseline: 7.6210x; 7.6210x over previous
//
#include <hip/hip_runtime.h>

// Disable FMA contraction so float rounding matches the numpy reference
// op-for-op (threshold compares at 0.5 and argmax ties depend on it).
#pragma clang fp contract(off)

#define BB 32     // batch
#define NN 100    // gt boxes per image
#define PP 8732   // priors
#define CH 16     // j-chunk for the transposed row-max reduce
#define LDW 257   // padded row stride (u32) -> 2-way banks only (free)
#define NBX 35    // blocks along the prior axis

// -------------------------------------------------------------------------
// Kernel 1 (r15): the verified r1 match pass + ENCODE TAIL.
//   r14 lesson: cg grid.sync costs ~700us on gfx950 -- never again. Instead:
//   8732-100 priors/batch are FINAL when their block finishes (forced
//   matches touch <=100 priors), and best_j/best_ov/pr are live in
//   registers. So the tail encodes loc/conf directly (m8 eliminated, full
//   k_encode pass eliminated); a tiny k_patch overwrites forced entries.
//  - Match machinery (s_iou chunk transpose, (iou<<32)|~p keys, strict->
//    scans, phantom-lane handling, phase B) is byte-identical to r1.
//  - Encode expressions textually identical to the verified k_encode.
//  - Exact IEEE f32 division kept -> bit-identical decisions vs reference.
// -------------------------------------------------------------------------
template <bool USE_PART>
__global__ __launch_bounds__(256) void k_match_enc(
    const float* __restrict__ gt,        // [B,N,4] xyxy
    const float* __restrict__ priors,    // [P,4] cxcywh
    const int*   __restrict__ labels,    // [B,N]
    unsigned long long* __restrict__ red,   // part [B][NBX][NN] or gkey [B][N]
    float* __restrict__ loc_out,         // [B,P,4]
    float* __restrict__ conf_out)        // [B,P]
{
    __shared__ unsigned int s_iou[CH * LDW];          // 16.4 KB
    __shared__ unsigned long long s_part[NN][17];     // 13.6 KB
    __shared__ float s_area[NN];                      // 400 B

    const int b = blockIdx.y;
    const int t = threadIdx.x;
    const int p = blockIdx.x * 256 + t;
    const bool valid = p < PP;
    const int pc = valid ? p : (PP - 1);

    // wave-uniform base: compiler scalarizes these loads (s_load_dwordx4)
    const float4* __restrict__ gtb =
        reinterpret_cast<const float4*>(gt) + b * NN;

    if (t < NN) {
        float4 g = gtb[t];                // per-thread gather here (vector)
        s_area[t] = (g.z - g.x) * (g.w - g.y);
    }

    const float4 pr = reinterpret_cast<const float4*>(priors)[pc];
    const float px1 = pr.x - pr.z * 0.5f;
    const float py1 = pr.y - pr.w * 0.5f;
    const float px2 = pr.x + pr.z * 0.5f;
    const float py2 = pr.y + pr.w * 0.5f;
    const float area_b = (px2 - px1) * (py2 - py1);

    float best_ov = -1.0f;
    int best_j = 0;

    __syncthreads();   // s_area ready

    for (int jc = 0; jc < NN; jc += CH) {
        const int nr = (NN - jc) < CH ? (NN - jc) : CH;

        #pragma unroll
        for (int jj = 0; jj < CH; ++jj) {
            if (jj >= nr) break;
            float4 g = gtb[jc + jj];                 // uniform -> SGPRs
            float area_a = s_area[jc + jj];          // broadcast ds_read
            float ltx = fmaxf(g.x, px1), lty = fmaxf(g.y, py1);
            float rbx = fminf(g.z, px2), rby = fminf(g.w, py2);
            float w = fmaxf(rbx - ltx, 0.0f), h = fmaxf(rby - lty, 0.0f);
            float inter = w * h;
            float iou = inter / (area_a + area_b - inter + 1e-6f);
            if (iou > best_ov) { best_ov = iou; best_j = jc + jj; }
            s_iou[jj * LDW + t] = __float_as_uint(iou);  // iou>=0: uint order
        }
        __syncthreads();

        // phase A: 16 threads per row, each scans 16 ascending-p columns
        {
            const int r = t & 15;
            const int s = t >> 4;
            if (r < nr) {
                const unsigned int* row = s_iou + r * LDW + s * 16;
                unsigned int bb = row[0];
                int bi = 0;
                #pragma unroll
                for (int i = 1; i < 16; ++i) {
                    unsigned int v = row[i];
                    if (v > bb) { bb = v; bi = i; }   // strict > = min p
                }
                int pw = blockIdx.x * 256 + s * 16 + bi;
                s_part[jc + r][s] = ((unsigned long long)bb << 32) |
                                    (unsigned int)(~pw);
            }
        }
        __syncthreads();   // s_iou reusable next chunk; s_part visible
    }

    // phase B: merge 16 segment partials per gt; plain store (or atomic)
    if (t < NN) {
        unsigned long long best = s_part[t][0];
        #pragma unroll
        for (int s = 1; s < 16; ++s) {
            unsigned long long k = s_part[t][s];
            if (k > best) best = k;                   // ~p breaks iou ties
        }
        if (USE_PART) {
            red[((size_t)b * NBX + blockIdx.x) * NN + t] = best;
        } else {
            atomicMax(&red[b * NN + t], best);
        }
    }

    // ---------------- encode tail (non-forced value; patch fixes forced) --
    if (valid) {
        const int lab  = labels[b * NN + best_j];
        const int conf = (best_ov < 0.5f) ? 0 : (lab + 1);

        const float4 g = gtb[best_j];   // divergent gather, L2-hot
        const float mcx = (g.x + g.z) * 0.5f;
        const float mcy = (g.y + g.w) * 0.5f;
        const float mw  = fmaxf(g.z - g.x, 1e-6f);
        const float mh  = fmaxf(g.w - g.y, 1e-6f);
        const float gcx = (mcx - pr.x) / (0.1f * pr.z);
        const float gcy = (mcy - pr.y) / (0.1f * pr.w);
        const float gw  = logf(mw / pr.z) / 0.2f;
        const float gh  = logf(mh / pr.w) / 0.2f;

        reinterpret_cast<float4*>(loc_out)[b * PP + p] =
            make_float4(gcx, gcy, gw, gh);
        conf_out[b * PP + p] = (float)conf;
    }
}

// -------------------------------------------------------------------------
// Kernel 2 (tiny): per batch, merge the 35 row-key partials (or read gkey),
// dedupe forced priors by MAX J (same winner as the verified
// atomicMax(s_forced, t) scatter), and overwrite the <=100 forced entries.
// Grid: BB blocks x 128 threads. Stream order guarantees k_match_enc's
// part/loc/conf writes are visible (same contract the verified 2-kernel
// path relied on).
// -------------------------------------------------------------------------
template <bool USE_PART>
__global__ __launch_bounds__(128) void k_patch(
    const float* __restrict__ gt,        // [B,N,4]
    const float* __restrict__ priors,    // [P,4]
    const int*   __restrict__ labels,    // [B,N]
    const unsigned long long* __restrict__ red,   // part or gkey
    float* __restrict__ loc_out,         // [B,P,4]
    float* __restrict__ conf_out)        // [B,P]
{
    __shared__ int s_pstar[NN];

    const int b = blockIdx.x;
    const int t = threadIdx.x;

    if (t < NN) {
        unsigned long long best;
        if (USE_PART) {
            const unsigned long long* q = red + (size_t)b * NBX * NN + t;
            best = q[0];
            #pragma unroll 5
            for (int bx = 1; bx < NBX; ++bx) {
                unsigned long long k = q[(size_t)bx * NN];
                if (k > best) best = k;               // ~p breaks iou ties
            }
        } else {
            best = red[b * NN + t];
        }
        s_pstar[t] = (int)~(unsigned int)(best & 0xFFFFFFFFull);
    }
    __syncthreads();

    if (t < NN) {
        const int p = s_pstar[t];
        // winner for duplicate p* = max j (matches atomicMax(s_forced, t))
        bool win = true;
        for (int j2 = t + 1; j2 < NN; ++j2)
            if (s_pstar[j2] == p) { win = false; break; }
        if (win) {
            const float4 g =
                reinterpret_cast<const float4*>(gt)[b * NN + t];
            const float4 pr = reinterpret_cast<const float4*>(priors)[p];
            const float mcx = (g.x + g.z) * 0.5f;
            const float mcy = (g.y + g.w) * 0.5f;
            const float mw  = fmaxf(g.z - g.x, 1e-6f);
            const float mh  = fmaxf(g.w - g.y, 1e-6f);
            const float gcx = (mcx - pr.x) / (0.1f * pr.z);
            const float gcy = (mcy - pr.y) / (0.1f * pr.w);
            const float gw  = logf(mw / pr.z) / 0.2f;
            const float gh  = logf(mh / pr.w) / 0.2f;

            reinterpret_cast<float4*>(loc_out)[b * PP + p] =
                make_float4(gcx, gcy, gw, gh);
            // forced match: ov forced to 2.0 in the reference -> never bg
            conf_out[b * PP + p] = (float)(labels[b * NN + t] + 1);
        }
    }
}

extern "C" void kernel_launch(void* const* d_in, const int* in_sizes, int n_in,
                              void* d_out, int out_size, void* d_ws, size_t ws_size,
                              hipStream_t stream) {
    const float* gt     = (const float*)d_in[0];  // [32,100,4] f32
    const int*   labels = (const int*)  d_in[1];  // [32,100] i32
    const float* priors = (const float*)d_in[2];  // [8732,4] f32

    float* loc  = (float*)d_out;                         // [32,8732,4]
    float* conf = (float*)d_out + (size_t)BB * PP * 4;   // [32,8732]

    const size_t part_bytes = (size_t)BB * NBX * NN * 8;   // 896,000
    dim3 grid(NBX, BB);

    if (ws_size >= part_bytes) {
        // atomic-free path: per-block partial keys, no memset dispatch
        unsigned long long* part = (unsigned long long*)d_ws;
        k_match_enc<true><<<grid, 256, 0, stream>>>(gt, priors, labels,
                                                    part, loc, conf);
        k_patch<true><<<BB, 128, 0, stream>>>(gt, priors, labels,
                                              part, loc, conf);
    } else {
        // fallback: gkey + atomicMax (needs zeroed keys)
        unsigned long long* gkey = (unsigned long long*)d_ws;    // [32,100]
        hipMemsetAsync(gkey, 0, (size_t)BB * NN * 8, stream);
        k_match_enc<false><<<grid, 256, 0, stream>>>(gt, priors, labels,
                                                     gkey, loc, conf);
        k_patch<false><<<BB, 128, 0, stream>>>(gt, priors, labels,
                                               gkey, loc, conf);
    }
}

// Round 17
// 95.347 us; speedup vs baseline: 8.2333x; 1.0803x over previous
//
#include <hip/hip_runtime.h>

// Disable FMA contraction so float rounding matches the numpy reference
// op-for-op (threshold compares at 0.5 and argmax ties depend on it).
#pragma clang fp contract(off)

#define BB 32     // batch
#define NN 100    // gt boxes per image
#define PP 8732   // priors
#define BPB 128   // priors per block (j-split: 256 thr = 128 priors x 2 halves)
#define HALF 50   // gt boxes per j-half
#define CH 16     // j-chunk for the transposed row-max reduce
#define LDW2 129  // padded row stride (u32): bank spread, 2-way max (free)
#define NSEG 8    // 128 priors / 16 per segment
#define NBX 69    // blocks along the prior axis (69*128 >= 8732)
#define EBX 35    // k_encode blocks (256 priors each)

// -------------------------------------------------------------------------
// Kernel 1 (j-split): thread owns (prior pl, j-half h) of batch b.
//   BEST-MEASURED VARIANT (r7: 95.8us total). Restored after r15's
//   encode-tail fusion regressed (103.0) -- the separate memory-bound
//   k_encode dispatch is cheaper than folding its divergent gather and
//   5 MB of stores into the compute-bound match kernel.
//  - Column argmax: each half tracks strict-> argmax over its own 50 js
//    (ascending), then half1's (ov,j) merges into half0 via LDS with
//    strict > -- exactly sequential first-occurrence over j=0..99.
//  - Row max: chunk-transpose: s_iou[32 rows][129] per chunk, phase A =
//    32 rows x 8 segs of 16 ascending-p cols, key = (iou<<32)|~p (max iou,
//    then min p), phase B merges 8 segs -> part[b][bx][j] (USE_PART) or
//    atomicMax (fallback).
//  - Out-of-range lanes compute the real IoU of prior PP-1: duplicate
//    columns tie with p=8731's value and lose the ~p min-p tie-break.
//  - Exact IEEE f32 division kept -> bit-identical decisions vs reference.
// -------------------------------------------------------------------------
template <bool USE_PART>
__global__ __launch_bounds__(256) void k_iou_pass(
    const float* __restrict__ gt,        // [B,N,4] xyxy
    const float* __restrict__ priors,    // [P,4] cxcywh
    unsigned long long* __restrict__ red,   // part [B][NBX][NN] or gkey [B][N]
    unsigned char* __restrict__ m8)         // [B,P]: best_j | (bg?0x80:0)
{
    __shared__ unsigned int s_iou[2 * CH][LDW2];        // 16.5 KB
    __shared__ unsigned long long s_part[NN][NSEG + 1]; // 7.2 KB
    __shared__ float s_area[NN];                        // 400 B
    __shared__ unsigned long long s_cmerge[BPB];        // 1 KB

    const int b = blockIdx.y;
    const int t = threadIdx.x;
    const int h  = t >> 7;          // j-half (wave-uniform: waves 0,1 vs 2,3)
    const int pl = t & 127;         // local prior
    const int p = blockIdx.x * BPB + pl;
    const bool valid = p < PP;
    const int pc = valid ? p : (PP - 1);
    const int j0 = h * HALF;

    // wave-uniform base: compiler scalarizes these loads (s_load_dwordx4)
    const float4* __restrict__ gtb =
        reinterpret_cast<const float4*>(gt) + b * NN;

    if (t < NN) {
        float4 g = gtb[t];                // per-thread gather here (vector)
        s_area[t] = (g.z - g.x) * (g.w - g.y);
    }

    const float4 pr = reinterpret_cast<const float4*>(priors)[pc];
    const float px1 = pr.x - pr.z * 0.5f;
    const float py1 = pr.y - pr.w * 0.5f;
    const float px2 = pr.x + pr.z * 0.5f;
    const float py2 = pr.y + pr.w * 0.5f;
    const float area_b = (px2 - px1) * (py2 - py1);

    float best_ov = -1.0f;
    int best_j = 0;

    __syncthreads();   // s_area ready

    for (int jc = 0; jc < HALF; jc += CH) {
        const int nr = (HALF - jc) < CH ? (HALF - jc) : CH;

        #pragma unroll
        for (int jj = 0; jj < CH; ++jj) {
            if (jj >= nr) break;
            const int j = j0 + jc + jj;
            float4 g = gtb[j];                 // uniform -> SGPRs
            float area_a = s_area[j];          // broadcast ds_read
            float ltx = fmaxf(g.x, px1), lty = fmaxf(g.y, py1);
            float rbx = fminf(g.z, px2), rby = fminf(g.w, py2);
            float w = fmaxf(rbx - ltx, 0.0f), h2 = fmaxf(rby - lty, 0.0f);
            float inter = w * h2;
            float iou = inter / (area_a + area_b - inter + 1e-6f);
            if (iou > best_ov) { best_ov = iou; best_j = j; }
            s_iou[h * CH + jj][pl] = __float_as_uint(iou); // iou>=0: uint order
        }
        __syncthreads();

        // phase A: 32 rows (16 per half) x 8 segs of 16 ascending-p columns
        {
            const int r = t & 31;          // s_iou row
            const int s = t >> 5;          // segment 0..7
            const int rr = r & 15;         // jj within the half
            const int rh = r >> 4;         // which half's rows
            if (rr < nr) {
                const unsigned int* row = &s_iou[r][s * 16];
                unsigned int bb = row[0];
                int bi = 0;
                #pragma unroll
                for (int i = 1; i < 16; ++i) {
                    unsigned int v = row[i];
                    if (v > bb) { bb = v; bi = i; }   // strict > = min p
                }
                int pw = blockIdx.x * BPB + s * 16 + bi;
                s_part[rh * HALF + jc + rr][s] =
                    ((unsigned long long)bb << 32) | (unsigned int)(~pw);
            }
        }
        __syncthreads();   // s_iou reusable next chunk; s_part visible
    }

    // column merge: half1 -> half0 (strict >: lower j wins ties, matching
    // sequential first-occurrence since all half0 js < half1 js)
    if (h == 1) {
        s_cmerge[pl] = ((unsigned long long)__float_as_uint(best_ov) << 32) |
                       (unsigned int)best_j;
    }
    __syncthreads();

    if (h == 0) {
        unsigned long long k1 = s_cmerge[pl];
        float ov1 = __uint_as_float((unsigned int)(k1 >> 32));
        int   j1  = (int)(k1 & 0xFFFFFFFFull);
        if (ov1 > best_ov) { best_ov = ov1; best_j = j1; }
        if (valid) {
            m8[b * PP + p] =
                (unsigned char)(best_j | ((best_ov < 0.5f) ? 0x80 : 0));
        }
    }

    // phase B: merge 8 segment partials per gt; plain store (or atomic)
    if (t < NN) {
        unsigned long long best = s_part[t][0];
        #pragma unroll
        for (int s = 1; s < NSEG; ++s) {
            unsigned long long k = s_part[t][s];
            if (k > best) best = k;                   // ~p breaks iou ties
        }
        if (USE_PART) {
            red[((size_t)b * NBX + blockIdx.x) * NN + t] = best;
        } else {
            atomicMax(&red[b * NN + t], best);
        }
    }
}

// -------------------------------------------------------------------------
// Kernel 2: reduce the 69 per-block row keys (USE_PART) or read gkey,
// scatter forced matches into LDS (max j = last-write-wins, matching the
// reference scatter), then encode. 256 priors per block (35 blocks).
// -------------------------------------------------------------------------
template <bool USE_PART>
__global__ __launch_bounds__(256) void k_encode(
    const float* __restrict__ gt,        // [B,N,4]
    const int*   __restrict__ labels,    // [B,N]
    const float* __restrict__ priors,    // [P,4]
    const unsigned long long* __restrict__ red,   // part or gkey
    const unsigned char* __restrict__ m8,         // [B,P]
    float* __restrict__ loc_out,         // [B,P,4]
    float* __restrict__ conf_out)        // [B,P]
{
    __shared__ int s_forced[256];        // local p -> forced gt j (-1 none)

    const int b = blockIdx.y;
    const int t = threadIdx.x;
    const int p = blockIdx.x * 256 + t;

    s_forced[t] = -1;
    __syncthreads();
    if (t < NN) {
        unsigned long long best;
        if (USE_PART) {
            const unsigned long long* q = red + (size_t)b * NBX * NN + t;
            best = q[0];
            #pragma unroll 4
            for (int bx = 1; bx < NBX; ++bx) {
                unsigned long long k = q[(size_t)bx * NN];
                if (k > best) best = k;
            }
        } else {
            best = red[b * NN + t];
        }
        int kp = (int)~(unsigned int)(best & 0xFFFFFFFFull);
        int lp = kp - blockIdx.x * 256;
        if ((unsigned)lp < 256u) atomicMax(&s_forced[lp], t);
    }
    __syncthreads();

    if (p >= PP) return;
    const int forced_j = s_forced[t];

    const unsigned char m = m8[b * PP + p];
    const int j    = (forced_j >= 0) ? forced_j : (m & 0x7f);
    const int lab  = labels[b * NN + j];
    const int conf = (forced_j < 0 && (m & 0x80)) ? 0 : (lab + 1);

    const float4 pr = reinterpret_cast<const float4*>(priors)[p];
    const float4 g  = reinterpret_cast<const float4*>(gt)[b * NN + j];
    const float mcx = (g.x + g.z) * 0.5f;
    const float mcy = (g.y + g.w) * 0.5f;
    const float mw  = fmaxf(g.z - g.x, 1e-6f);
    const float mh  = fmaxf(g.w - g.y, 1e-6f);
    const float gcx = (mcx - pr.x) / (0.1f * pr.z);
    const float gcy = (mcy - pr.y) / (0.1f * pr.w);
    const float gw  = logf(mw / pr.z) / 0.2f;
    const float gh  = logf(mh / pr.w) / 0.2f;

    reinterpret_cast<float4*>(loc_out)[b * PP + p] =
        make_float4(gcx, gcy, gw, gh);
    conf_out[b * PP + p] = (float)conf;
}

extern "C" void kernel_launch(void* const* d_in, const int* in_sizes, int n_in,
                              void* d_out, int out_size, void* d_ws, size_t ws_size,
                              hipStream_t stream) {
    const float* gt     = (const float*)d_in[0];  // [32,100,4] f32
    const int*   labels = (const int*)  d_in[1];  // [32,100] i32
    const float* priors = (const float*)d_in[2];  // [8732,4] f32

    float* loc  = (float*)d_out;                         // [32,8732,4]
    float* conf = (float*)d_out + (size_t)BB * PP * 4;   // [32,8732]

    const size_t part_bytes = (size_t)BB * NBX * NN * 8;   // 1,766,400
    const size_t m8_bytes   = (size_t)BB * PP;             // 279,424
    dim3 grid_i(NBX, BB);
    dim3 grid_e(EBX, BB);

    if (ws_size >= part_bytes + m8_bytes) {
        // atomic-free path: per-block partial keys, no memset dispatch
        unsigned long long* part = (unsigned long long*)d_ws;
        unsigned char* m8 = (unsigned char*)d_ws + part_bytes;
        k_iou_pass<true><<<grid_i, 256, 0, stream>>>(gt, priors, part, m8);
        k_encode<true><<<grid_e, 256, 0, stream>>>(gt, labels, priors, part,
                                                   m8, loc, conf);
    } else {
        // fallback: gkey + atomicMax (needs zeroed keys)
        unsigned long long* gkey = (unsigned long long*)d_ws;        // [32,100]
        unsigned char* m8 = (unsigned char*)d_ws + (size_t)BB * NN * 8;
        hipMemsetAsync(gkey, 0, (size_t)BB * NN * 8, stream);
        k_iou_pass<false><<<grid_i, 256, 0, stream>>>(gt, priors, gkey, m8);
        k_encode<false><<<grid_e, 256, 0, stream>>>(gt, labels, priors, gkey,
                                                    m8, loc, conf);
    }
}